// Round 1
// baseline (14552.798 us; speedup 1.0000x reference)
//
#include <hip/hip_runtime.h>

#define B_ 32
#define S_ 512
#define D_ 768
#define H_ 1024
#define L_ 4
#define TH 3072  // 3*H

typedef unsigned short u16;
typedef __bf16 bf16x8 __attribute__((ext_vector_type(8)));
typedef float f32x4 __attribute__((ext_vector_type(4)));

__device__ __forceinline__ u16 f2b(float f) {
  unsigned u = __builtin_bit_cast(unsigned, f);
  u += 0x7fffu + ((u >> 16) & 1u);  // RNE
  return (u16)(u >> 16);
}
__device__ __forceinline__ float b2f(u16 h) {
  return __builtin_bit_cast(float, ((unsigned)h) << 16);
}
__device__ __forceinline__ unsigned pack2(float a, float b) {
  return (unsigned)f2b(a) | ((unsigned)f2b(b) << 16);
}

// ---------------- fp32 -> bf16 convert ----------------
__global__ __launch_bounds__(256) void cvt_kernel(const float* __restrict__ src,
                                                  u16* __restrict__ dst, int n4) {
  int i = blockIdx.x * 256 + threadIdx.x;
  int stride = gridDim.x * 256;
  for (; i < n4; i += stride) {
    float4 f = ((const float4*)src)[i];
    uint2 o;
    o.x = pack2(f.x, f.y);
    o.y = pack2(f.z, f.w);
    ((uint2*)dst)[i] = o;
  }
}

// ---------------- GI0 = (x+pos) @ W_ih0^T + b_ih[0]  -> bf16 [S*B][3072] ----------------
// A rows indexed (s*B + b); fused x+pos staging.
__global__ __launch_bounds__(256) void gi0_gemm(const float* __restrict__ x,
                                                const float* __restrict__ pos,
                                                const u16* __restrict__ W0,
                                                const float* __restrict__ bih0,
                                                u16* __restrict__ GI0) {
  const int n0 = blockIdx.x * 64;  // 48 tiles
  const int m0 = blockIdx.y * 64;  // 256 tiles
  __shared__ u16 sA[64 * 72];
  __shared__ u16 sB[64 * 72];
  const int tid = threadIdx.x, lane = tid & 63, wid = tid >> 6;
  const int wm = wid >> 1, wn = wid & 1;
  const int fr = lane & 15, fk = (lane >> 4) * 8;
  f32x4 acc[2][2] = {};
  for (int k0 = 0; k0 < D_; k0 += 64) {
    for (int sl = tid; sl < 512; sl += 256) {
      int r = sl >> 3, c = sl & 7;
      int m = m0 + r, si = m >> 5, b = m & 31;
      const float* xp = x + (size_t)((b << 9) + si) * D_ + k0 + c * 8;
      const float* pp = pos + (size_t)si * D_ + k0 + c * 8;
      float4 x0 = *(const float4*)xp, x1 = *(const float4*)(xp + 4);
      float4 p0 = *(const float4*)pp, p1 = *(const float4*)(pp + 4);
      uint4 o;
      o.x = pack2(x0.x + p0.x, x0.y + p0.y);
      o.y = pack2(x0.z + p0.z, x0.w + p0.w);
      o.z = pack2(x1.x + p1.x, x1.y + p1.y);
      o.w = pack2(x1.z + p1.z, x1.w + p1.w);
      *(uint4*)&sA[r * 72 + c * 8] = o;
      *(uint4*)&sB[r * 72 + c * 8] =
          *(const uint4*)(W0 + (size_t)(n0 + r) * D_ + k0 + c * 8);
    }
    __syncthreads();
#pragma unroll
    for (int kk = 0; kk < 2; ++kk) {
      bf16x8 a0 = *(const bf16x8*)&sA[(wm * 32 + fr) * 72 + kk * 32 + fk];
      bf16x8 a1 = *(const bf16x8*)&sA[(wm * 32 + 16 + fr) * 72 + kk * 32 + fk];
      bf16x8 b0 = *(const bf16x8*)&sB[(wn * 32 + fr) * 72 + kk * 32 + fk];
      bf16x8 b1 = *(const bf16x8*)&sB[(wn * 32 + 16 + fr) * 72 + kk * 32 + fk];
      acc[0][0] = __builtin_amdgcn_mfma_f32_16x16x32_bf16(a0, b0, acc[0][0], 0, 0, 0);
      acc[0][1] = __builtin_amdgcn_mfma_f32_16x16x32_bf16(a0, b1, acc[0][1], 0, 0, 0);
      acc[1][0] = __builtin_amdgcn_mfma_f32_16x16x32_bf16(a1, b0, acc[1][0], 0, 0, 0);
      acc[1][1] = __builtin_amdgcn_mfma_f32_16x16x32_bf16(a1, b1, acc[1][1], 0, 0, 0);
    }
    __syncthreads();
  }
#pragma unroll
  for (int mi = 0; mi < 2; ++mi)
#pragma unroll
    for (int ni = 0; ni < 2; ++ni)
#pragma unroll
      for (int r = 0; r < 4; ++r) {
        int m = m0 + wm * 32 + mi * 16 + (lane >> 4) * 4 + r;
        int n = n0 + wn * 32 + ni * 16 + fr;
        GI0[(size_t)m * TH + n] = f2b(acc[mi][ni][r] + bih0[n]);
      }
}

// ---------------- out_seq = H3 @ W_out^T + b_out  (row remap [b,s] <- [s,b]) ----------------
__global__ __launch_bounds__(256) void out_gemm(const u16* __restrict__ H3,
                                                const u16* __restrict__ Wo,
                                                const float* __restrict__ bo,
                                                float* __restrict__ out) {
  const int n0 = blockIdx.x * 64;  // 12 tiles
  const int m0 = blockIdx.y * 64;  // 256 tiles
  __shared__ u16 sA[64 * 72];
  __shared__ u16 sB[64 * 72];
  const int tid = threadIdx.x, lane = tid & 63, wid = tid >> 6;
  const int wm = wid >> 1, wn = wid & 1;
  const int fr = lane & 15, fk = (lane >> 4) * 8;
  f32x4 acc[2][2] = {};
  for (int k0 = 0; k0 < H_; k0 += 64) {
    for (int sl = tid; sl < 512; sl += 256) {
      int r = sl >> 3, c = sl & 7;
      int m = m0 + r, b = m >> 9, si = m & 511;
      *(uint4*)&sA[r * 72 + c * 8] =
          *(const uint4*)(H3 + (size_t)((si << 5) + b) * H_ + k0 + c * 8);
      *(uint4*)&sB[r * 72 + c * 8] =
          *(const uint4*)(Wo + (size_t)(n0 + r) * H_ + k0 + c * 8);
    }
    __syncthreads();
#pragma unroll
    for (int kk = 0; kk < 2; ++kk) {
      bf16x8 a0 = *(const bf16x8*)&sA[(wm * 32 + fr) * 72 + kk * 32 + fk];
      bf16x8 a1 = *(const bf16x8*)&sA[(wm * 32 + 16 + fr) * 72 + kk * 32 + fk];
      bf16x8 b0 = *(const bf16x8*)&sB[(wn * 32 + fr) * 72 + kk * 32 + fk];
      bf16x8 b1 = *(const bf16x8*)&sB[(wn * 32 + 16 + fr) * 72 + kk * 32 + fk];
      acc[0][0] = __builtin_amdgcn_mfma_f32_16x16x32_bf16(a0, b0, acc[0][0], 0, 0, 0);
      acc[0][1] = __builtin_amdgcn_mfma_f32_16x16x32_bf16(a0, b1, acc[0][1], 0, 0, 0);
      acc[1][0] = __builtin_amdgcn_mfma_f32_16x16x32_bf16(a1, b0, acc[1][0], 0, 0, 0);
      acc[1][1] = __builtin_amdgcn_mfma_f32_16x16x32_bf16(a1, b1, acc[1][1], 0, 0, 0);
    }
    __syncthreads();
  }
#pragma unroll
  for (int mi = 0; mi < 2; ++mi)
#pragma unroll
    for (int ni = 0; ni < 2; ++ni)
#pragma unroll
      for (int r = 0; r < 4; ++r) {
        int m = m0 + wm * 32 + mi * 16 + (lane >> 4) * 4 + r;
        int n = n0 + wn * 32 + ni * 16 + fr;
        out[(size_t)m * D_ + n] = acc[mi][ni][r] + bo[n];
      }
}

// ---------------- one wavefront step: all active layers ----------------
// grid 256 blocks (layer = bid>>6, 16 gate-triples per block), 384 threads (6 waves).
// wave (mw = wid&1, g = wid>>1): 16x16 D tile, M = batch half, N = 16 rows of gate g.
__global__ __launch_bounds__(384) void step_kernel(
    int s, const u16* __restrict__ Whh, const u16* __restrict__ Wih,
    const u16* __restrict__ GI0, const float* __restrict__ bih,
    const float* __restrict__ bhh, u16* __restrict__ hrbf, float* __restrict__ hrf,
    u16* __restrict__ H3, float* __restrict__ hsf) {
  const int l = blockIdx.x >> 6;
  const int t = s - l;
  if (t < 0 || t >= S_) return;
  const int n0 = (blockIdx.x & 63) << 4;
  const int tid = threadIdx.x, lane = tid & 63, wid = tid >> 6;
  const int mw = wid & 1, g = wid >> 1;
  const int prev = (s - 1) & 1, cur = s & 1;
  __shared__ u16 shp[32 * 136];
  __shared__ u16 shi[32 * 136];
  __shared__ float shacc[2][3][2][16][16];  // [gi/gh][gate][mw][b][j]

  const u16* hp_bf = hrbf + ((l * 2 + prev) << 15);
  const u16* hi_bf = (l > 0) ? hrbf + (((l - 1) * 2 + prev) << 15) : (const u16*)0;
  const int fr = lane & 15, fk = (lane >> 4) * 8;
  const u16* Wh = Whh + ((size_t)(l * TH + (g << 10) + n0 + fr) << 10);
  const u16* Wi = (l > 0) ? Wih + ((size_t)((l - 1) * TH + (g << 10) + n0 + fr) << 10)
                          : (const u16*)0;
  f32x4 acc_h = {0.f, 0.f, 0.f, 0.f};
  f32x4 acc_i = {0.f, 0.f, 0.f, 0.f};

  for (int kc = 0; kc < H_; kc += 128) {
    for (int sl = tid; sl < 512; sl += 384) {
      int r = sl >> 4, c = sl & 15;
      *(uint4*)&shp[r * 136 + c * 8] = *(const uint4*)(hp_bf + (r << 10) + kc + c * 8);
      if (l > 0)
        *(uint4*)&shi[r * 136 + c * 8] = *(const uint4*)(hi_bf + (r << 10) + kc + c * 8);
    }
    __syncthreads();
#pragma unroll
    for (int kk = 0; kk < 4; ++kk) {
      int lofs = (mw * 16 + fr) * 136 + kk * 32 + fk;
      bf16x8 a = *(const bf16x8*)&shp[lofs];
      bf16x8 b = *(const bf16x8*)(Wh + kc + kk * 32 + fk);
      acc_h = __builtin_amdgcn_mfma_f32_16x16x32_bf16(a, b, acc_h, 0, 0, 0);
      if (l > 0) {
        bf16x8 a2 = *(const bf16x8*)&shi[lofs];
        bf16x8 b2 = *(const bf16x8*)(Wi + kc + kk * 32 + fk);
        acc_i = __builtin_amdgcn_mfma_f32_16x16x32_bf16(a2, b2, acc_i, 0, 0, 0);
      }
    }
    __syncthreads();
  }
#pragma unroll
  for (int r = 0; r < 4; ++r) {
    shacc[1][g][mw][(lane >> 4) * 4 + r][fr] = acc_h[r];
    if (l > 0) shacc[0][g][mw][(lane >> 4) * 4 + r][fr] = acc_i[r];
  }
  __syncthreads();

  // gate math: 512 outputs = 32 batch x 16 triples
  for (int o = tid; o < 512; o += 384) {
    int b = o >> 4, i = o & 15;
    int j = n0 + i;
    int mw2 = b >> 4, bi = b & 15;
    float i_r, i_z, i_n;
    if (l == 0) {
      const u16* gp = GI0 + (size_t)((t << 5) + b) * TH + j;
      i_r = b2f(gp[0]);
      i_z = b2f(gp[1024]);
      i_n = b2f(gp[2048]);
    } else {
      const float* bp = bih + l * TH + j;
      i_r = shacc[0][0][mw2][bi][i] + bp[0];
      i_z = shacc[0][1][mw2][bi][i] + bp[1024];
      i_n = shacc[0][2][mw2][bi][i] + bp[2048];
    }
    const float* bh = bhh + l * TH + j;
    float h_r = shacc[1][0][mw2][bi][i] + bh[0];
    float h_z = shacc[1][1][mw2][bi][i] + bh[1024];
    float h_n = shacc[1][2][mw2][bi][i] + bh[2048];
    float hp = hrf[((l * 2 + prev) << 15) + (b << 10) + j];
    float rr = 1.f / (1.f + __expf(-(i_r + h_r)));
    float zz = 1.f / (1.f + __expf(-(i_z + h_z)));
    float nn = tanhf(i_n + rr * h_n);
    float hn = (1.f - zz) * nn + zz * hp;
    int oidx = ((l * 2 + cur) << 15) + (b << 10) + j;
    hrf[oidx] = hn;
    hrbf[oidx] = f2b(hn);
    if (l == 3) H3[((size_t)((t << 5) + b) << 10) + j] = f2b(hn);
    if (t == S_ - 1) hsf[(((l << 5) + b) << 10) + j] = hn;
  }
}

extern "C" void kernel_launch(void* const* d_in, const int* in_sizes, int n_in,
                              void* d_out, int out_size, void* d_ws, size_t ws_size,
                              hipStream_t stream) {
  const float* x = (const float*)d_in[0];
  const float* pos = (const float*)d_in[1];
  const float* Wih0 = (const float*)d_in[2];
  const float* Wih = (const float*)d_in[3];
  const float* Whh = (const float*)d_in[4];
  const float* bih = (const float*)d_in[5];
  const float* bhh = (const float*)d_in[6];
  const float* Wout = (const float*)d_in[7];
  const float* bout = (const float*)d_in[8];
  float* out = (float*)d_out;

  char* ws = (char*)d_ws;
  size_t o = 0;
  u16* wih0_b = (u16*)(ws + o); o += (size_t)TH * D_ * 2;
  u16* wih_b  = (u16*)(ws + o); o += (size_t)3 * TH * H_ * 2;
  u16* whh_b  = (u16*)(ws + o); o += (size_t)4 * TH * H_ * 2;
  u16* wout_b = (u16*)(ws + o); o += (size_t)D_ * H_ * 2;
  u16* GI0    = (u16*)(ws + o); o += (size_t)S_ * B_ * TH * 2;
  u16* H3     = (u16*)(ws + o); o += (size_t)S_ * B_ * H_ * 2;
  u16* hrbf   = (u16*)(ws + o); o += (size_t)L_ * 2 * B_ * H_ * 2;
  float* hrf  = (float*)(ws + o); o += (size_t)L_ * 2 * B_ * H_ * 4;

  cvt_kernel<<<512, 256, 0, stream>>>(Wih0, wih0_b, TH * D_ / 4);
  cvt_kernel<<<512, 256, 0, stream>>>(Wih, wih_b, 3 * TH * H_ / 4);
  cvt_kernel<<<512, 256, 0, stream>>>(Whh, whh_b, 4 * TH * H_ / 4);
  cvt_kernel<<<512, 256, 0, stream>>>(Wout, wout_b, D_ * H_ / 4);
  hipMemsetAsync(hrbf, 0, (size_t)L_ * 2 * B_ * H_ * 6, stream);

  gi0_gemm<<<dim3(TH / 64, (S_ * B_) / 64), 256, 0, stream>>>(x, pos, wih0_b, bih, GI0);

  for (int s = 0; s < S_ + L_ - 1; ++s)
    step_kernel<<<256, 384, 0, stream>>>(s, whh_b, wih_b, GI0, bih, bhh, hrbf, hrf, H3,
                                         out + (size_t)B_ * S_ * D_);

  out_gemm<<<dim3(D_ / 64, (S_ * B_) / 64), 256, 0, stream>>>(H3, wout_b, bout, out);
}

// Round 4
// 6543.751 us; speedup vs baseline: 2.2239x; 2.2239x over previous
//
#include <hip/hip_runtime.h>

#define B_ 32
#define S_ 512
#define D_ 768
#define H_ 1024
#define L_ 4
#define TH 3072  // 3*H
#define NPL 64   // blocks per layer
#define NITER (S_ + L_ - 1)

typedef unsigned short u16;
typedef unsigned int u32;
typedef __bf16 bf16x8 __attribute__((ext_vector_type(8)));
typedef float f32x4 __attribute__((ext_vector_type(4)));

__device__ __forceinline__ u16 f2b(float f) {
  unsigned u = __builtin_bit_cast(unsigned, f);
  u += 0x7fffu + ((u >> 16) & 1u);  // RNE
  return (u16)(u >> 16);
}
__device__ __forceinline__ float b2f(u16 h) {
  return __builtin_bit_cast(float, ((unsigned)h) << 16);
}
__device__ __forceinline__ unsigned pack2(float a, float b) {
  return (unsigned)f2b(a) | ((unsigned)f2b(b) << 16);
}

// ---------------- fp32 -> bf16 convert ----------------
__global__ __launch_bounds__(256) void cvt_kernel(const float* __restrict__ src,
                                                  u16* __restrict__ dst, int n4) {
  int i = blockIdx.x * 256 + threadIdx.x;
  int stride = gridDim.x * 256;
  for (; i < n4; i += stride) {
    float4 f = ((const float4*)src)[i];
    uint2 o;
    o.x = pack2(f.x, f.y);
    o.y = pack2(f.z, f.w);
    ((uint2*)dst)[i] = o;
  }
}

// ---------------- GI0 = (x+pos) @ W_ih0^T + b_ih[0]  -> bf16 [S*B][3072] ----------------
__global__ __launch_bounds__(256) void gi0_gemm(const float* __restrict__ x,
                                                const float* __restrict__ pos,
                                                const u16* __restrict__ W0,
                                                const float* __restrict__ bih0,
                                                u16* __restrict__ GI0) {
  const int n0 = blockIdx.x * 64;
  const int m0 = blockIdx.y * 64;
  __shared__ u16 sA[64 * 72];
  __shared__ u16 sB[64 * 72];
  const int tid = threadIdx.x, lane = tid & 63, wid = tid >> 6;
  const int wm = wid >> 1, wn = wid & 1;
  const int fr = lane & 15, fk = (lane >> 4) * 8;
  f32x4 acc[2][2] = {};
  for (int k0 = 0; k0 < D_; k0 += 64) {
    for (int sl = tid; sl < 512; sl += 256) {
      int r = sl >> 3, c = sl & 7;
      int m = m0 + r, si = m >> 5, b = m & 31;
      const float* xp = x + (size_t)((b << 9) + si) * D_ + k0 + c * 8;
      const float* pp = pos + (size_t)si * D_ + k0 + c * 8;
      float4 x0 = *(const float4*)xp, x1 = *(const float4*)(xp + 4);
      float4 p0 = *(const float4*)pp, p1 = *(const float4*)(pp + 4);
      uint4 o;
      o.x = pack2(x0.x + p0.x, x0.y + p0.y);
      o.y = pack2(x0.z + p0.z, x0.w + p0.w);
      o.z = pack2(x1.x + p1.x, x1.y + p1.y);
      o.w = pack2(x1.z + p1.z, x1.w + p1.w);
      *(uint4*)&sA[r * 72 + c * 8] = o;
      *(uint4*)&sB[r * 72 + c * 8] =
          *(const uint4*)(W0 + (size_t)(n0 + r) * D_ + k0 + c * 8);
    }
    __syncthreads();
#pragma unroll
    for (int kk = 0; kk < 2; ++kk) {
      bf16x8 a0 = *(const bf16x8*)&sA[(wm * 32 + fr) * 72 + kk * 32 + fk];
      bf16x8 a1 = *(const bf16x8*)&sA[(wm * 32 + 16 + fr) * 72 + kk * 32 + fk];
      bf16x8 b0 = *(const bf16x8*)&sB[(wn * 32 + fr) * 72 + kk * 32 + fk];
      bf16x8 b1 = *(const bf16x8*)&sB[(wn * 32 + 16 + fr) * 72 + kk * 32 + fk];
      acc[0][0] = __builtin_amdgcn_mfma_f32_16x16x32_bf16(a0, b0, acc[0][0], 0, 0, 0);
      acc[0][1] = __builtin_amdgcn_mfma_f32_16x16x32_bf16(a0, b1, acc[0][1], 0, 0, 0);
      acc[1][0] = __builtin_amdgcn_mfma_f32_16x16x32_bf16(a1, b0, acc[1][0], 0, 0, 0);
      acc[1][1] = __builtin_amdgcn_mfma_f32_16x16x32_bf16(a1, b1, acc[1][1], 0, 0, 0);
    }
    __syncthreads();
  }
#pragma unroll
  for (int mi = 0; mi < 2; ++mi)
#pragma unroll
    for (int ni = 0; ni < 2; ++ni)
#pragma unroll
      for (int r = 0; r < 4; ++r) {
        int m = m0 + wm * 32 + mi * 16 + (lane >> 4) * 4 + r;
        int n = n0 + wn * 32 + ni * 16 + fr;
        GI0[(size_t)m * TH + n] = f2b(acc[mi][ni][r] + bih0[n]);
      }
}

// ---------------- out_seq = H3 @ W_out^T + b_out ----------------
__global__ __launch_bounds__(256) void out_gemm(const u16* __restrict__ H3,
                                                const u16* __restrict__ Wo,
                                                const float* __restrict__ bo,
                                                float* __restrict__ out) {
  const int n0 = blockIdx.x * 64;
  const int m0 = blockIdx.y * 64;
  __shared__ u16 sA[64 * 72];
  __shared__ u16 sB[64 * 72];
  const int tid = threadIdx.x, lane = tid & 63, wid = tid >> 6;
  const int wm = wid >> 1, wn = wid & 1;
  const int fr = lane & 15, fk = (lane >> 4) * 8;
  f32x4 acc[2][2] = {};
  for (int k0 = 0; k0 < H_; k0 += 64) {
    for (int sl = tid; sl < 512; sl += 256) {
      int r = sl >> 3, c = sl & 7;
      int m = m0 + r, b = m >> 9, si = m & 511;
      *(uint4*)&sA[r * 72 + c * 8] =
          *(const uint4*)(H3 + (size_t)((si << 5) + b) * H_ + k0 + c * 8);
      *(uint4*)&sB[r * 72 + c * 8] =
          *(const uint4*)(Wo + (size_t)(n0 + r) * H_ + k0 + c * 8);
    }
    __syncthreads();
#pragma unroll
    for (int kk = 0; kk < 2; ++kk) {
      bf16x8 a0 = *(const bf16x8*)&sA[(wm * 32 + fr) * 72 + kk * 32 + fk];
      bf16x8 a1 = *(const bf16x8*)&sA[(wm * 32 + 16 + fr) * 72 + kk * 32 + fk];
      bf16x8 b0 = *(const bf16x8*)&sB[(wn * 32 + fr) * 72 + kk * 32 + fk];
      bf16x8 b1 = *(const bf16x8*)&sB[(wn * 32 + 16 + fr) * 72 + kk * 32 + fk];
      acc[0][0] = __builtin_amdgcn_mfma_f32_16x16x32_bf16(a0, b0, acc[0][0], 0, 0, 0);
      acc[0][1] = __builtin_amdgcn_mfma_f32_16x16x32_bf16(a0, b1, acc[0][1], 0, 0, 0);
      acc[1][0] = __builtin_amdgcn_mfma_f32_16x16x32_bf16(a1, b0, acc[1][0], 0, 0, 0);
      acc[1][1] = __builtin_amdgcn_mfma_f32_16x16x32_bf16(a1, b1, acc[1][1], 0, 0, 0);
    }
    __syncthreads();
  }
#pragma unroll
  for (int mi = 0; mi < 2; ++mi)
#pragma unroll
    for (int ni = 0; ni < 2; ++ni)
#pragma unroll
      for (int r = 0; r < 4; ++r) {
        int m = m0 + wm * 32 + mi * 16 + (lane >> 4) * 4 + r;
        int n = n0 + wn * 32 + ni * 16 + fr;
        out[(size_t)m * D_ + n] = acc[mi][ni][r] + bo[n];
      }
}

// ---------------- persistent weight-stationary GRU scan ----------------
// PLAIN launch: 256 blocks (= #CUs), __launch_bounds__(256,1) + ~384 VGPRs
// guarantees 1 block/CU => all blocks co-resident => spin-wait protocol has
// guaranteed forward progress. No cooperative API.
// h state 4-deep ring: [L][4][32][1024]. Writer (l, s) uses buf s&3; the
// conflicting reader generation (l+1 @ s-3) is protected by
// cnt[l+1] >= (s-2)*NPL.
__global__ __launch_bounds__(256, 1) void rnn_persist(
    const u16* __restrict__ Whh, const u16* __restrict__ Wih,
    const u16* __restrict__ GI0, const float* __restrict__ bih,
    const float* __restrict__ bhh, u16* __restrict__ hg /* [L][4][32][1024] */,
    int* cnt, u16* __restrict__ H3, float* __restrict__ hsf) {
  const int bid = blockIdx.x;
  const int l = bid >> 6;
  const int n0 = (bid & 63) << 4;
  const int tid = threadIdx.x, lane = tid & 63, wid = tid >> 6;
  const int fr = lane & 15, q = lane >> 4;

  __shared__ float red[4][3][32][17];

  // ---- preload weights into registers ----
  bf16x8 w[3][16];
  if (l == 0) {
    const int kb = wid << 8;  // K-quarter of Whh[0]
#pragma unroll
    for (int g = 0; g < 3; ++g)
#pragma unroll
      for (int kt = 0; kt < 8; ++kt)
        w[g][kt] = *(const bf16x8*)(Whh + (((size_t)((g << 10) + n0 + fr)) << 10) +
                                    kb + kt * 32 + q * 8);
  } else {
    const u16* Wp = (wid < 2) ? (Wih + (((size_t)(l - 1) * TH) << 10))
                              : (Whh + (((size_t)l * TH) << 10));
    const int kb = (wid & 1) << 9;  // K-half
#pragma unroll
    for (int g = 0; g < 3; ++g)
#pragma unroll
      for (int kt = 0; kt < 16; ++kt)
        w[g][kt] = *(const bf16x8*)(Wp + (((size_t)((g << 10) + n0 + fr)) << 10) +
                                    kb + kt * 32 + q * 8);
  }

  // gate-phase mapping: thread handles outputs (gb, gj) and (gb, gj+1)
  const int gb = tid >> 3;
  const int gjj = (tid & 7) * 2;
  const int gj = n0 + gjj;
  float bihv[3][2], bhhv[3][2];
#pragma unroll
  for (int g = 0; g < 3; ++g) {
    if (l > 0) {
      bihv[g][0] = bih[l * TH + (g << 10) + gj];
      bihv[g][1] = bih[l * TH + (g << 10) + gj + 1];
    } else {
      bihv[g][0] = bihv[g][1] = 0.f;
    }
    bhhv[g][0] = bhh[l * TH + (g << 10) + gj];
    bhhv[g][1] = bhh[l * TH + (g << 10) + gj + 1];
  }
  float hpriv0 = 0.f, hpriv1 = 0.f;  // fp32 master copy of this thread's h pair
  __syncthreads();

  for (int s = 0; s < NITER; ++s) {
    const int t = s - l;
    if (t < 0 || t >= S_) {
      if (tid == 0)
        __hip_atomic_fetch_add(&cnt[l], 1, __ATOMIC_RELAXED, __HIP_MEMORY_SCOPE_AGENT);
      continue;
    }
    const int prev = (s - 1) & 3;

    // ---- wait: producers done (cnt >= s*NPL), ring-buffer free (l+1 done s-3) ----
    if (wid == 0) {
      const int tgt = s * NPL;
      for (;;) {
        int ok = 1;
        ok &= (__hip_atomic_load(&cnt[l], __ATOMIC_RELAXED, __HIP_MEMORY_SCOPE_AGENT) >= tgt);
        if (l > 0)
          ok &= (__hip_atomic_load(&cnt[l - 1], __ATOMIC_RELAXED, __HIP_MEMORY_SCOPE_AGENT) >= tgt);
        if (l < 3)
          ok &= (__hip_atomic_load(&cnt[l + 1], __ATOMIC_RELAXED, __HIP_MEMORY_SCOPE_AGENT) >=
                 tgt - 2 * NPL);
        if (ok) break;
        __builtin_amdgcn_s_sleep(2);
      }
    }
    __syncthreads();

    // ---- MFMA phase: A-fragments straight from IF (sc0 sc1), weights from VGPRs ----
    f32x4 acc[2][3] = {};
    if (l == 0) {
      const u16* hp = hg + ((0 | prev) << 15);
      const int kb = wid << 8;
      bf16x8 afr[2][8];
#pragma unroll
      for (int mt = 0; mt < 2; ++mt)
#pragma unroll
        for (int kt = 0; kt < 8; ++kt) {
          const u16* p = hp + (((mt << 4) + fr) << 10) + kb + kt * 32 + q * 8;
          asm volatile("global_load_dwordx4 %0, %1, off sc0 sc1"
                       : "=v"(afr[mt][kt]) : "v"(p) : "memory");
        }
      asm volatile("s_waitcnt vmcnt(0)" ::: "memory");
      __builtin_amdgcn_sched_barrier(0);
#pragma unroll
      for (int kt = 0; kt < 8; ++kt)
#pragma unroll
        for (int g = 0; g < 3; ++g) {
          acc[0][g] = __builtin_amdgcn_mfma_f32_16x16x32_bf16(afr[0][kt], w[g][kt], acc[0][g], 0, 0, 0);
          acc[1][g] = __builtin_amdgcn_mfma_f32_16x16x32_bf16(afr[1][kt], w[g][kt], acc[1][g], 0, 0, 0);
        }
    } else {
      const u16* hsrc = (wid < 2) ? (hg + ((((l - 1) << 2) | prev) << 15))
                                  : (hg + (((l << 2) | prev) << 15));
      const int kb = (wid & 1) << 9;
      bf16x8 afr[2][16];
#pragma unroll
      for (int mt = 0; mt < 2; ++mt)
#pragma unroll
        for (int kt = 0; kt < 16; ++kt) {
          const u16* p = hsrc + (((mt << 4) + fr) << 10) + kb + kt * 32 + q * 8;
          asm volatile("global_load_dwordx4 %0, %1, off sc0 sc1"
                       : "=v"(afr[mt][kt]) : "v"(p) : "memory");
        }
      asm volatile("s_waitcnt vmcnt(0)" ::: "memory");
      __builtin_amdgcn_sched_barrier(0);
#pragma unroll
      for (int kt = 0; kt < 16; ++kt)
#pragma unroll
        for (int g = 0; g < 3; ++g) {
          acc[0][g] = __builtin_amdgcn_mfma_f32_16x16x32_bf16(afr[0][kt], w[g][kt], acc[0][g], 0, 0, 0);
          acc[1][g] = __builtin_amdgcn_mfma_f32_16x16x32_bf16(afr[1][kt], w[g][kt], acc[1][g], 0, 0, 0);
        }
    }

    // ---- write partial sums to LDS ----
#pragma unroll
    for (int mt = 0; mt < 2; ++mt)
#pragma unroll
      for (int g = 0; g < 3; ++g)
#pragma unroll
        for (int r = 0; r < 4; ++r)
          red[wid][g][(mt << 4) + q * 4 + r][fr] = acc[mt][g][r];
    __syncthreads();

    // ---- gate math: 2 outputs per thread ----
    float gi[3][2], gh[3][2];
#pragma unroll
    for (int g = 0; g < 3; ++g)
#pragma unroll
      for (int u = 0; u < 2; ++u) {
        float s01 = red[0][g][gb][gjj + u] + red[1][g][gb][gjj + u];
        float s23 = red[2][g][gb][gjj + u] + red[3][g][gb][gjj + u];
        if (l == 0) {
          gh[g][u] = s01 + s23 + bhhv[g][u];
        } else {
          gi[g][u] = s01 + bihv[g][u];
          gh[g][u] = s23 + bhhv[g][u];
        }
      }
    if (l == 0) {
      const u16* gp = GI0 + (size_t)((t << 5) + gb) * TH + gj;
#pragma unroll
      for (int u = 0; u < 2; ++u) {
        gi[0][u] = b2f(gp[u]);
        gi[1][u] = b2f(gp[1024 + u]);
        gi[2][u] = b2f(gp[2048 + u]);
      }
    }
    float hn[2];
    float hpv[2] = {hpriv0, hpriv1};
#pragma unroll
    for (int u = 0; u < 2; ++u) {
      float rr = 1.f / (1.f + __expf(-(gi[0][u] + gh[0][u])));
      float zz = 1.f / (1.f + __expf(-(gi[1][u] + gh[1][u])));
      float nn = tanhf(gi[2][u] + rr * gh[2][u]);
      hn[u] = (1.f - zz) * nn + zz * hpv[u];
    }
    hpriv0 = hn[0];
    hpriv1 = hn[1];
    u32 hpack = pack2(hn[0], hn[1]);
    u32* hd = (u32*)(hg + (((l << 2) | (s & 3)) << 15) + (gb << 10) + gj);
    asm volatile("global_store_dword %0, %1, off sc0 sc1" ::"v"(hd), "v"(hpack)
                 : "memory");
    if (l == 3) *(u32*)(H3 + (((size_t)(t << 5) + gb) << 10) + gj) = hpack;
    if (t == S_ - 1) {
      hsf[((l << 5) + gb) * 1024 + gj] = hn[0];
      hsf[((l << 5) + gb) * 1024 + gj + 1] = hn[1];
    }
    asm volatile("s_waitcnt vmcnt(0)" ::: "memory");
    __syncthreads();
    if (tid == 0)
      __hip_atomic_fetch_add(&cnt[l], 1, __ATOMIC_RELAXED, __HIP_MEMORY_SCOPE_AGENT);
  }
}

extern "C" void kernel_launch(void* const* d_in, const int* in_sizes, int n_in,
                              void* d_out, int out_size, void* d_ws, size_t ws_size,
                              hipStream_t stream) {
  const float* x = (const float*)d_in[0];
  const float* pos = (const float*)d_in[1];
  const float* Wih0 = (const float*)d_in[2];
  const float* Wih = (const float*)d_in[3];
  const float* Whh = (const float*)d_in[4];
  const float* bih = (const float*)d_in[5];
  const float* bhh = (const float*)d_in[6];
  const float* Wout = (const float*)d_in[7];
  const float* bout = (const float*)d_in[8];
  float* out = (float*)d_out;

  char* ws = (char*)d_ws;
  size_t o = 0;
  u16* wih0_b = (u16*)(ws + o); o += (size_t)TH * D_ * 2;
  u16* wih_b  = (u16*)(ws + o); o += (size_t)3 * TH * H_ * 2;
  u16* whh_b  = (u16*)(ws + o); o += (size_t)4 * TH * H_ * 2;
  u16* wout_b = (u16*)(ws + o); o += (size_t)D_ * H_ * 2;
  u16* GI0    = (u16*)(ws + o); o += (size_t)S_ * B_ * TH * 2;
  u16* H3     = (u16*)(ws + o); o += (size_t)S_ * B_ * H_ * 2;
  u16* hg     = (u16*)(ws + o); o += (size_t)L_ * 4 * B_ * H_ * 2;
  int* cnt    = (int*)(ws + o); o += 256;

  cvt_kernel<<<512, 256, 0, stream>>>(Wih0, wih0_b, TH * D_ / 4);
  cvt_kernel<<<512, 256, 0, stream>>>(Wih, wih_b, 3 * TH * H_ / 4);
  cvt_kernel<<<512, 256, 0, stream>>>(Whh, whh_b, 4 * TH * H_ / 4);
  cvt_kernel<<<512, 256, 0, stream>>>(Wout, wout_b, D_ * H_ / 4);
  hipMemsetAsync(hg, 0, (size_t)L_ * 4 * B_ * H_ * 2 + 256, stream);

  gi0_gemm<<<dim3(TH / 64, (S_ * B_) / 64), 256, 0, stream>>>(x, pos, wih0_b, bih, GI0);

  float* hsf = out + (size_t)B_ * S_ * D_;
  rnn_persist<<<256, 256, 0, stream>>>(whh_b, wih_b, GI0, bih, bhh, hg, cnt, H3, hsf);

  out_gemm<<<dim3(D_ / 64, (S_ * B_) / 64), 256, 0, stream>>>(H3, wout_b, bout, out);
}

// Round 5
// 6070.246 us; speedup vs baseline: 2.3974x; 1.0780x over previous
//
#include <hip/hip_runtime.h>

#define B_ 32
#define S_ 512
#define D_ 768
#define H_ 1024
#define L_ 4
#define TH 3072  // 3*H
#define NPL 64   // blocks per layer
#define NITER (S_ + L_ - 1)

typedef unsigned short u16;
typedef unsigned int u32;
typedef __bf16 bf16x8 __attribute__((ext_vector_type(8)));
typedef float f32x4 __attribute__((ext_vector_type(4)));
typedef int i32x4 __attribute__((ext_vector_type(4)));

__device__ __forceinline__ u16 f2b(float f) {
  unsigned u = __builtin_bit_cast(unsigned, f);
  u += 0x7fffu + ((u >> 16) & 1u);  // RNE
  return (u16)(u >> 16);
}
__device__ __forceinline__ float b2f(u16 h) {
  return __builtin_bit_cast(float, ((unsigned)h) << 16);
}
__device__ __forceinline__ unsigned pack2(float a, float b) {
  return (unsigned)f2b(a) | ((unsigned)f2b(b) << 16);
}

// ---------------- fp32 -> bf16 convert ----------------
__global__ __launch_bounds__(256) void cvt_kernel(const float* __restrict__ src,
                                                  u16* __restrict__ dst, int n4) {
  int i = blockIdx.x * 256 + threadIdx.x;
  int stride = gridDim.x * 256;
  for (; i < n4; i += stride) {
    float4 f = ((const float4*)src)[i];
    uint2 o;
    o.x = pack2(f.x, f.y);
    o.y = pack2(f.z, f.w);
    ((uint2*)dst)[i] = o;
  }
}

// ---------------- GI0 = (x+pos) @ W_ih0^T + b_ih[0]  -> bf16 [S*B][3072] ----------------
__global__ __launch_bounds__(256) void gi0_gemm(const float* __restrict__ x,
                                                const float* __restrict__ pos,
                                                const u16* __restrict__ W0,
                                                const float* __restrict__ bih0,
                                                u16* __restrict__ GI0) {
  const int n0 = blockIdx.x * 64;
  const int m0 = blockIdx.y * 64;
  __shared__ u16 sA[64 * 72];
  __shared__ u16 sB[64 * 72];
  const int tid = threadIdx.x, lane = tid & 63, wid = tid >> 6;
  const int wm = wid >> 1, wn = wid & 1;
  const int fr = lane & 15, fk = (lane >> 4) * 8;
  f32x4 acc[2][2] = {};
  for (int k0 = 0; k0 < D_; k0 += 64) {
    for (int sl = tid; sl < 512; sl += 256) {
      int r = sl >> 3, c = sl & 7;
      int m = m0 + r, si = m >> 5, b = m & 31;
      const float* xp = x + (size_t)((b << 9) + si) * D_ + k0 + c * 8;
      const float* pp = pos + (size_t)si * D_ + k0 + c * 8;
      float4 x0 = *(const float4*)xp, x1 = *(const float4*)(xp + 4);
      float4 p0 = *(const float4*)pp, p1 = *(const float4*)(pp + 4);
      uint4 o;
      o.x = pack2(x0.x + p0.x, x0.y + p0.y);
      o.y = pack2(x0.z + p0.z, x0.w + p0.w);
      o.z = pack2(x1.x + p1.x, x1.y + p1.y);
      o.w = pack2(x1.z + p1.z, x1.w + p1.w);
      *(uint4*)&sA[r * 72 + c * 8] = o;
      *(uint4*)&sB[r * 72 + c * 8] =
          *(const uint4*)(W0 + (size_t)(n0 + r) * D_ + k0 + c * 8);
    }
    __syncthreads();
#pragma unroll
    for (int kk = 0; kk < 2; ++kk) {
      bf16x8 a0 = *(const bf16x8*)&sA[(wm * 32 + fr) * 72 + kk * 32 + fk];
      bf16x8 a1 = *(const bf16x8*)&sA[(wm * 32 + 16 + fr) * 72 + kk * 32 + fk];
      bf16x8 b0 = *(const bf16x8*)&sB[(wn * 32 + fr) * 72 + kk * 32 + fk];
      bf16x8 b1 = *(const bf16x8*)&sB[(wn * 32 + 16 + fr) * 72 + kk * 32 + fk];
      acc[0][0] = __builtin_amdgcn_mfma_f32_16x16x32_bf16(a0, b0, acc[0][0], 0, 0, 0);
      acc[0][1] = __builtin_amdgcn_mfma_f32_16x16x32_bf16(a0, b1, acc[0][1], 0, 0, 0);
      acc[1][0] = __builtin_amdgcn_mfma_f32_16x16x32_bf16(a1, b0, acc[1][0], 0, 0, 0);
      acc[1][1] = __builtin_amdgcn_mfma_f32_16x16x32_bf16(a1, b1, acc[1][1], 0, 0, 0);
    }
    __syncthreads();
  }
#pragma unroll
  for (int mi = 0; mi < 2; ++mi)
#pragma unroll
    for (int ni = 0; ni < 2; ++ni)
#pragma unroll
      for (int r = 0; r < 4; ++r) {
        int m = m0 + wm * 32 + mi * 16 + (lane >> 4) * 4 + r;
        int n = n0 + wn * 32 + ni * 16 + fr;
        GI0[(size_t)m * TH + n] = f2b(acc[mi][ni][r] + bih0[n]);
      }
}

// ---------------- out_seq = H3 @ W_out^T + b_out ----------------
__global__ __launch_bounds__(256) void out_gemm(const u16* __restrict__ H3,
                                                const u16* __restrict__ Wo,
                                                const float* __restrict__ bo,
                                                float* __restrict__ out) {
  const int n0 = blockIdx.x * 64;
  const int m0 = blockIdx.y * 64;
  __shared__ u16 sA[64 * 72];
  __shared__ u16 sB[64 * 72];
  const int tid = threadIdx.x, lane = tid & 63, wid = tid >> 6;
  const int wm = wid >> 1, wn = wid & 1;
  const int fr = lane & 15, fk = (lane >> 4) * 8;
  f32x4 acc[2][2] = {};
  for (int k0 = 0; k0 < H_; k0 += 64) {
    for (int sl = tid; sl < 512; sl += 256) {
      int r = sl >> 3, c = sl & 7;
      int m = m0 + r, b = m >> 9, si = m & 511;
      *(uint4*)&sA[r * 72 + c * 8] =
          *(const uint4*)(H3 + (size_t)((si << 5) + b) * H_ + k0 + c * 8);
      *(uint4*)&sB[r * 72 + c * 8] =
          *(const uint4*)(Wo + (size_t)(n0 + r) * H_ + k0 + c * 8);
    }
    __syncthreads();
#pragma unroll
    for (int kk = 0; kk < 2; ++kk) {
      bf16x8 a0 = *(const bf16x8*)&sA[(wm * 32 + fr) * 72 + kk * 32 + fk];
      bf16x8 a1 = *(const bf16x8*)&sA[(wm * 32 + 16 + fr) * 72 + kk * 32 + fk];
      bf16x8 b0 = *(const bf16x8*)&sB[(wn * 32 + fr) * 72 + kk * 32 + fk];
      bf16x8 b1 = *(const bf16x8*)&sB[(wn * 32 + 16 + fr) * 72 + kk * 32 + fk];
      acc[0][0] = __builtin_amdgcn_mfma_f32_16x16x32_bf16(a0, b0, acc[0][0], 0, 0, 0);
      acc[0][1] = __builtin_amdgcn_mfma_f32_16x16x32_bf16(a0, b1, acc[0][1], 0, 0, 0);
      acc[1][0] = __builtin_amdgcn_mfma_f32_16x16x32_bf16(a1, b0, acc[1][0], 0, 0, 0);
      acc[1][1] = __builtin_amdgcn_mfma_f32_16x16x32_bf16(a1, b1, acc[1][1], 0, 0, 0);
    }
    __syncthreads();
  }
#pragma unroll
  for (int mi = 0; mi < 2; ++mi)
#pragma unroll
    for (int ni = 0; ni < 2; ++ni)
#pragma unroll
      for (int r = 0; r < 4; ++r) {
        int m = m0 + wm * 32 + mi * 16 + (lane >> 4) * 4 + r;
        int n = n0 + wn * 32 + ni * 16 + fr;
        out[(size_t)m * D_ + n] = acc[mi][ni][r] + bo[n];
      }
}

// ---------------- persistent weight-stationary GRU scan ----------------
// 256 blocks (1/CU), plain launch. h state 4-deep ring [L][4][32][1024].
// Writer (l,s) -> buf s&3; conflicting reader gen (l+1 @ s-3) protected by
// cnt[l+1] >= (s-2)*NPL. All 4 counters in one 16B line, polled by a single
// lane with one global_load_dwordx4 sc0 sc1 per round.
__global__ __launch_bounds__(256, 1) void rnn_persist(
    const u16* __restrict__ Whh, const u16* __restrict__ Wih,
    const u16* __restrict__ GI0, const float* __restrict__ bih,
    const float* __restrict__ bhh, u16* __restrict__ hg /* [L][4][32][1024] */,
    int* cnt, u16* __restrict__ H3, float* __restrict__ hsf) {
  const int bid = blockIdx.x;
  const int l = bid >> 6;
  const int n0 = (bid & 63) << 4;
  const int tid = threadIdx.x, lane = tid & 63, wid = tid >> 6;
  const int fr = lane & 15, q = lane >> 4;

  __shared__ float red[4][3][32][17];

  // ---- preload weights into registers ----
  bf16x8 w[3][16];
  if (l == 0) {
    const int kb = wid << 8;  // K-quarter of Whh[0]
#pragma unroll
    for (int g = 0; g < 3; ++g)
#pragma unroll
      for (int kt = 0; kt < 8; ++kt)
        w[g][kt] = *(const bf16x8*)(Whh + (((size_t)((g << 10) + n0 + fr)) << 10) +
                                    kb + kt * 32 + q * 8);
  } else {
    const u16* Wp = (wid < 2) ? (Wih + (((size_t)(l - 1) * TH) << 10))
                              : (Whh + (((size_t)l * TH) << 10));
    const int kb = (wid & 1) << 9;  // K-half
#pragma unroll
    for (int g = 0; g < 3; ++g)
#pragma unroll
      for (int kt = 0; kt < 16; ++kt)
        w[g][kt] = *(const bf16x8*)(Wp + (((size_t)((g << 10) + n0 + fr)) << 10) +
                                    kb + kt * 32 + q * 8);
  }

  // gate-phase mapping: thread handles outputs (gb, gj) and (gb, gj+1)
  const int gb = tid >> 3;
  const int gjj = (tid & 7) * 2;
  const int gj = n0 + gjj;
  float bihv[3][2], bhhv[3][2];
#pragma unroll
  for (int g = 0; g < 3; ++g) {
    if (l > 0) {
      bihv[g][0] = bih[l * TH + (g << 10) + gj];
      bihv[g][1] = bih[l * TH + (g << 10) + gj + 1];
    } else {
      bihv[g][0] = bihv[g][1] = 0.f;
    }
    bhhv[g][0] = bhh[l * TH + (g << 10) + gj];
    bhhv[g][1] = bhh[l * TH + (g << 10) + gj + 1];
  }
  float hpriv0 = 0.f, hpriv1 = 0.f;  // fp32 master copy of this thread's h pair
  __syncthreads();

  for (int s = 0; s < NITER; ++s) {
    const int t = s - l;
    if (t < 0 || t >= S_) {
      if (tid == 0)
        __hip_atomic_fetch_add(&cnt[l], 1, __ATOMIC_RELAXED, __HIP_MEMORY_SCOPE_AGENT);
      continue;
    }
    const int prev = (s - 1) & 3;

    // ---- prefetch GI0 (independent of handshake) ----
    u32 g0p = 0, g1p = 0, g2p = 0;
    if (l == 0) {
      const u16* gp = GI0 + (size_t)((t << 5) + gb) * TH + gj;
      g0p = *(const u32*)gp;
      g1p = *(const u32*)(gp + 1024);
      g2p = *(const u32*)(gp + 2048);
    }

    // ---- single-lane poll: one dwordx4 of all 4 counters per round ----
    if (tid == 0) {
      const int tgt = s * NPL;
      for (;;) {
        i32x4 c;
        asm volatile("global_load_dwordx4 %0, %1, off sc0 sc1\n\ts_waitcnt vmcnt(0)"
                     : "=v"(c) : "v"(cnt) : "memory");
        int c0 = c[0], c1 = c[1], c2 = c[2], c3 = c[3];
        int cown = (l == 0) ? c0 : (l == 1) ? c1 : (l == 2) ? c2 : c3;
        int cm1 = (l == 1) ? c0 : (l == 2) ? c1 : c2;
        int cp1 = (l == 0) ? c1 : (l == 1) ? c2 : c3;
        bool ok = (cown >= tgt) && (l == 0 || cm1 >= tgt) &&
                  (l == 3 || cp1 >= tgt - 2 * NPL);
        if (ok) break;
        __builtin_amdgcn_s_sleep(1);
      }
    }
    __syncthreads();

    // ---- MFMA phase: A-fragments straight from IF (sc0 sc1), weights from VGPRs ----
    f32x4 acc[2][3] = {};
    if (l == 0) {
      const u16* hp = hg + ((0 | prev) << 15);
      const int kb = wid << 8;
      bf16x8 afr[2][8];
#pragma unroll
      for (int mt = 0; mt < 2; ++mt)
#pragma unroll
        for (int kt = 0; kt < 8; ++kt) {
          const u16* p = hp + (((mt << 4) + fr) << 10) + kb + kt * 32 + q * 8;
          asm volatile("global_load_dwordx4 %0, %1, off sc0 sc1"
                       : "=v"(afr[mt][kt]) : "v"(p) : "memory");
        }
      asm volatile("s_waitcnt vmcnt(0)" ::: "memory");
      __builtin_amdgcn_sched_barrier(0);
#pragma unroll
      for (int kt = 0; kt < 8; ++kt)
#pragma unroll
        for (int g = 0; g < 3; ++g) {
          acc[0][g] = __builtin_amdgcn_mfma_f32_16x16x32_bf16(afr[0][kt], w[g][kt], acc[0][g], 0, 0, 0);
          acc[1][g] = __builtin_amdgcn_mfma_f32_16x16x32_bf16(afr[1][kt], w[g][kt], acc[1][g], 0, 0, 0);
        }
    } else {
      const u16* hsrc = (wid < 2) ? (hg + ((((l - 1) << 2) | prev) << 15))
                                  : (hg + (((l << 2) | prev) << 15));
      const int kb = (wid & 1) << 9;
      bf16x8 afr[2][16];
#pragma unroll
      for (int mt = 0; mt < 2; ++mt)
#pragma unroll
        for (int kt = 0; kt < 16; ++kt) {
          const u16* p = hsrc + (((mt << 4) + fr) << 10) + kb + kt * 32 + q * 8;
          asm volatile("global_load_dwordx4 %0, %1, off sc0 sc1"
                       : "=v"(afr[mt][kt]) : "v"(p) : "memory");
        }
      asm volatile("s_waitcnt vmcnt(0)" ::: "memory");
      __builtin_amdgcn_sched_barrier(0);
#pragma unroll
      for (int kt = 0; kt < 16; ++kt)
#pragma unroll
        for (int g = 0; g < 3; ++g) {
          acc[0][g] = __builtin_amdgcn_mfma_f32_16x16x32_bf16(afr[0][kt], w[g][kt], acc[0][g], 0, 0, 0);
          acc[1][g] = __builtin_amdgcn_mfma_f32_16x16x32_bf16(afr[1][kt], w[g][kt], acc[1][g], 0, 0, 0);
        }
    }

    // ---- write partial sums to LDS ----
#pragma unroll
    for (int mt = 0; mt < 2; ++mt)
#pragma unroll
      for (int g = 0; g < 3; ++g)
#pragma unroll
        for (int r = 0; r < 4; ++r)
          red[wid][g][(mt << 4) + q * 4 + r][fr] = acc[mt][g][r];
    __syncthreads();

    // ---- gate math: 2 outputs per thread ----
    float gi[3][2], gh[3][2];
#pragma unroll
    for (int g = 0; g < 3; ++g)
#pragma unroll
      for (int u = 0; u < 2; ++u) {
        float s01 = red[0][g][gb][gjj + u] + red[1][g][gb][gjj + u];
        float s23 = red[2][g][gb][gjj + u] + red[3][g][gb][gjj + u];
        if (l == 0) {
          gh[g][u] = s01 + s23 + bhhv[g][u];
        } else {
          gi[g][u] = s01 + bihv[g][u];
          gh[g][u] = s23 + bhhv[g][u];
        }
      }
    if (l == 0) {
      gi[0][0] = b2f((u16)(g0p & 0xffff));
      gi[0][1] = b2f((u16)(g0p >> 16));
      gi[1][0] = b2f((u16)(g1p & 0xffff));
      gi[1][1] = b2f((u16)(g1p >> 16));
      gi[2][0] = b2f((u16)(g2p & 0xffff));
      gi[2][1] = b2f((u16)(g2p >> 16));
    }
    float hn[2];
    float hpv[2] = {hpriv0, hpriv1};
#pragma unroll
    for (int u = 0; u < 2; ++u) {
      float rr = 1.f / (1.f + __expf(-(gi[0][u] + gh[0][u])));
      float zz = 1.f / (1.f + __expf(-(gi[1][u] + gh[1][u])));
      float xn = gi[2][u] + rr * gh[2][u];
      float nn = 1.f - 2.f / (__expf(2.f * xn) + 1.f);  // tanh, saturates correctly
      hn[u] = (1.f - zz) * nn + zz * hpv[u];
    }
    hpriv0 = hn[0];
    hpriv1 = hn[1];
    u32 hpack = pack2(hn[0], hn[1]);
    u32* hd = (u32*)(hg + (((l << 2) | (s & 3)) << 15) + (gb << 10) + gj);
    asm volatile("global_store_dword %0, %1, off sc0 sc1" ::"v"(hd), "v"(hpack)
                 : "memory");
    asm volatile("s_waitcnt vmcnt(0)" ::: "memory");
    __syncthreads();
    if (tid == 0)
      __hip_atomic_fetch_add(&cnt[l], 1, __ATOMIC_RELAXED, __HIP_MEMORY_SCOPE_AGENT);
    // non-protocol stores off the release path:
    if (l == 3) *(u32*)(H3 + (((size_t)(t << 5) + gb) << 10) + gj) = hpack;
    if (t == S_ - 1) {
      hsf[((l << 5) + gb) * 1024 + gj] = hn[0];
      hsf[((l << 5) + gb) * 1024 + gj + 1] = hn[1];
    }
  }
}

extern "C" void kernel_launch(void* const* d_in, const int* in_sizes, int n_in,
                              void* d_out, int out_size, void* d_ws, size_t ws_size,
                              hipStream_t stream) {
  const float* x = (const float*)d_in[0];
  const float* pos = (const float*)d_in[1];
  const float* Wih0 = (const float*)d_in[2];
  const float* Wih = (const float*)d_in[3];
  const float* Whh = (const float*)d_in[4];
  const float* bih = (const float*)d_in[5];
  const float* bhh = (const float*)d_in[6];
  const float* Wout = (const float*)d_in[7];
  const float* bout = (const float*)d_in[8];
  float* out = (float*)d_out;

  char* ws = (char*)d_ws;
  size_t o = 0;
  u16* wih0_b = (u16*)(ws + o); o += (size_t)TH * D_ * 2;
  u16* wih_b  = (u16*)(ws + o); o += (size_t)3 * TH * H_ * 2;
  u16* whh_b  = (u16*)(ws + o); o += (size_t)4 * TH * H_ * 2;
  u16* wout_b = (u16*)(ws + o); o += (size_t)D_ * H_ * 2;
  u16* GI0    = (u16*)(ws + o); o += (size_t)S_ * B_ * TH * 2;
  u16* H3     = (u16*)(ws + o); o += (size_t)S_ * B_ * H_ * 2;
  u16* hg     = (u16*)(ws + o); o += (size_t)L_ * 4 * B_ * H_ * 2;
  int* cnt    = (int*)(ws + o); o += 256;

  cvt_kernel<<<512, 256, 0, stream>>>(Wih0, wih0_b, TH * D_ / 4);
  cvt_kernel<<<512, 256, 0, stream>>>(Wih, wih_b, 3 * TH * H_ / 4);
  cvt_kernel<<<512, 256, 0, stream>>>(Whh, whh_b, 4 * TH * H_ / 4);
  cvt_kernel<<<512, 256, 0, stream>>>(Wout, wout_b, D_ * H_ / 4);
  hipMemsetAsync(hg, 0, (size_t)L_ * 4 * B_ * H_ * 2 + 256, stream);

  gi0_gemm<<<dim3(TH / 64, (S_ * B_) / 64), 256, 0, stream>>>(x, pos, wih0_b, bih, GI0);

  float* hsf = out + (size_t)B_ * S_ * D_;
  rnn_persist<<<256, 256, 0, stream>>>(whh_b, wih_b, GI0, bih, bhh, hg, cnt, H3, hsf);

  out_gemm<<<dim3(D_ / 64, (S_ * B_) / 64), 256, 0, stream>>>(H3, wout_b, bout, out);
}

// Round 9
// 5585.406 us; speedup vs baseline: 2.6055x; 1.0868x over previous
//
#include <hip/hip_runtime.h>

#define B_ 32
#define S_ 512
#define D_ 768
#define H_ 1024
#define L_ 4
#define TH 3072  // 3*H
#define NPL 64   // blocks per layer
#define NITER (S_ + L_ - 1)

typedef unsigned short u16;
typedef unsigned int u32;
typedef __bf16 bf16x8 __attribute__((ext_vector_type(8)));
typedef float f32x4 __attribute__((ext_vector_type(4)));

__device__ __forceinline__ u16 f2b(float f) {
  unsigned u = __builtin_bit_cast(unsigned, f);
  u += 0x7fffu + ((u >> 16) & 1u);  // RNE
  return (u16)(u >> 16);
}
__device__ __forceinline__ float b2f(u16 h) {
  return __builtin_bit_cast(float, ((unsigned)h) << 16);
}
__device__ __forceinline__ unsigned pack2(float a, float b) {
  return (unsigned)f2b(a) | ((unsigned)f2b(b) << 16);
}

// ---------------- fp32 -> bf16 convert ----------------
__global__ __launch_bounds__(256) void cvt_kernel(const float* __restrict__ src,
                                                  u16* __restrict__ dst, int n4) {
  int i = blockIdx.x * 256 + threadIdx.x;
  int stride = gridDim.x * 256;
  for (; i < n4; i += stride) {
    float4 f = ((const float4*)src)[i];
    uint2 o;
    o.x = pack2(f.x, f.y);
    o.y = pack2(f.z, f.w);
    ((uint2*)dst)[i] = o;
  }
}

// ---------------- GI0 = (x+pos) @ W_ih0^T + b_ih[0]  -> bf16 [S*B][3072] ----------------
__global__ __launch_bounds__(256) void gi0_gemm(const float* __restrict__ x,
                                                const float* __restrict__ pos,
                                                const u16* __restrict__ W0,
                                                const float* __restrict__ bih0,
                                                u16* __restrict__ GI0) {
  const int n0 = blockIdx.x * 64;
  const int m0 = blockIdx.y * 64;
  __shared__ u16 sA[64 * 72];
  __shared__ u16 sB[64 * 72];
  const int tid = threadIdx.x, lane = tid & 63, wid = tid >> 6;
  const int wm = wid >> 1, wn = wid & 1;
  const int fr = lane & 15, fk = (lane >> 4) * 8;
  f32x4 acc[2][2] = {};
  for (int k0 = 0; k0 < D_; k0 += 64) {
    for (int sl = tid; sl < 512; sl += 256) {
      int r = sl >> 3, c = sl & 7;
      int m = m0 + r, si = m >> 5, b = m & 31;
      const float* xp = x + (size_t)((b << 9) + si) * D_ + k0 + c * 8;
      const float* pp = pos + (size_t)si * D_ + k0 + c * 8;
      float4 x0 = *(const float4*)xp, x1 = *(const float4*)(xp + 4);
      float4 p0 = *(const float4*)pp, p1 = *(const float4*)(pp + 4);
      uint4 o;
      o.x = pack2(x0.x + p0.x, x0.y + p0.y);
      o.y = pack2(x0.z + p0.z, x0.w + p0.w);
      o.z = pack2(x1.x + p1.x, x1.y + p1.y);
      o.w = pack2(x1.z + p1.z, x1.w + p1.w);
      *(uint4*)&sA[r * 72 + c * 8] = o;
      *(uint4*)&sB[r * 72 + c * 8] =
          *(const uint4*)(W0 + (size_t)(n0 + r) * D_ + k0 + c * 8);
    }
    __syncthreads();
#pragma unroll
    for (int kk = 0; kk < 2; ++kk) {
      bf16x8 a0 = *(const bf16x8*)&sA[(wm * 32 + fr) * 72 + kk * 32 + fk];
      bf16x8 a1 = *(const bf16x8*)&sA[(wm * 32 + 16 + fr) * 72 + kk * 32 + fk];
      bf16x8 b0 = *(const bf16x8*)&sB[(wn * 32 + fr) * 72 + kk * 32 + fk];
      bf16x8 b1 = *(const bf16x8*)&sB[(wn * 32 + 16 + fr) * 72 + kk * 32 + fk];
      acc[0][0] = __builtin_amdgcn_mfma_f32_16x16x32_bf16(a0, b0, acc[0][0], 0, 0, 0);
      acc[0][1] = __builtin_amdgcn_mfma_f32_16x16x32_bf16(a0, b1, acc[0][1], 0, 0, 0);
      acc[1][0] = __builtin_amdgcn_mfma_f32_16x16x32_bf16(a1, b0, acc[1][0], 0, 0, 0);
      acc[1][1] = __builtin_amdgcn_mfma_f32_16x16x32_bf16(a1, b1, acc[1][1], 0, 0, 0);
    }
    __syncthreads();
  }
#pragma unroll
  for (int mi = 0; mi < 2; ++mi)
#pragma unroll
    for (int ni = 0; ni < 2; ++ni)
#pragma unroll
      for (int r = 0; r < 4; ++r) {
        int m = m0 + wm * 32 + mi * 16 + (lane >> 4) * 4 + r;
        int n = n0 + wn * 32 + ni * 16 + fr;
        GI0[(size_t)m * TH + n] = f2b(acc[mi][ni][r] + bih0[n]);
      }
}

// ---------------- out_seq = H3 @ W_out^T + b_out ----------------
__global__ __launch_bounds__(256) void out_gemm(const u16* __restrict__ H3,
                                                const u16* __restrict__ Wo,
                                                const float* __restrict__ bo,
                                                float* __restrict__ out) {
  const int n0 = blockIdx.x * 64;
  const int m0 = blockIdx.y * 64;
  __shared__ u16 sA[64 * 72];
  __shared__ u16 sB[64 * 72];
  const int tid = threadIdx.x, lane = tid & 63, wid = tid >> 6;
  const int wm = wid >> 1, wn = wid & 1;
  const int fr = lane & 15, fk = (lane >> 4) * 8;
  f32x4 acc[2][2] = {};
  for (int k0 = 0; k0 < H_; k0 += 64) {
    for (int sl = tid; sl < 512; sl += 256) {
      int r = sl >> 3, c = sl & 7;
      int m = m0 + r, b = m >> 9, si = m & 511;
      *(uint4*)&sA[r * 72 + c * 8] =
          *(const uint4*)(H3 + (size_t)((si << 5) + b) * H_ + k0 + c * 8);
      *(uint4*)&sB[r * 72 + c * 8] =
          *(const uint4*)(Wo + (size_t)(n0 + r) * H_ + k0 + c * 8);
    }
    __syncthreads();
#pragma unroll
    for (int kk = 0; kk < 2; ++kk) {
      bf16x8 a0 = *(const bf16x8*)&sA[(wm * 32 + fr) * 72 + kk * 32 + fk];
      bf16x8 a1 = *(const bf16x8*)&sA[(wm * 32 + 16 + fr) * 72 + kk * 32 + fk];
      bf16x8 b0 = *(const bf16x8*)&sB[(wn * 32 + fr) * 72 + kk * 32 + fk];
      bf16x8 b1 = *(const bf16x8*)&sB[(wn * 32 + 16 + fr) * 72 + kk * 32 + fk];
      acc[0][0] = __builtin_amdgcn_mfma_f32_16x16x32_bf16(a0, b0, acc[0][0], 0, 0, 0);
      acc[0][1] = __builtin_amdgcn_mfma_f32_16x16x32_bf16(a0, b1, acc[0][1], 0, 0, 0);
      acc[1][0] = __builtin_amdgcn_mfma_f32_16x16x32_bf16(a1, b0, acc[1][0], 0, 0, 0);
      acc[1][1] = __builtin_amdgcn_mfma_f32_16x16x32_bf16(a1, b1, acc[1][1], 0, 0, 0);
    }
    __syncthreads();
  }
#pragma unroll
  for (int mi = 0; mi < 2; ++mi)
#pragma unroll
    for (int ni = 0; ni < 2; ++ni)
#pragma unroll
      for (int r = 0; r < 4; ++r) {
        int m = m0 + wm * 32 + mi * 16 + (lane >> 4) * 4 + r;
        int n = n0 + wn * 32 + ni * 16 + fr;
        out[(size_t)m * D_ + n] = acc[mi][ni][r] + bo[n];
      }
}

// ---------------- persistent weight-stationary GRU scan ----------------
// 256 blocks (1/CU). Distributed flags: flags[L][64], one 64B line per block,
// flag = #completed iterations. Publication: uncontended RELEASE fetch_add.
// POLL FIX (rule #18): the 3 flag loads + s_waitcnt vmcnt(0) live in ONE asm
// statement, so the dependent compares can never be scheduled between the
// loads and the waitcnt (the rounds-6..8 bug: stale-VGPR reads made the poll
// pass one step early). Boundary layers clamp f_m1/f_p1 to f_own.
// h ring [L][4][32][1024]: writer (l,s)->buf s&3; WAR vs (l+1 @ s-3) guarded
// by flag[l+1] >= s-2; producers by flag[l-1] >= s, flag[l] >= s.
__global__ __launch_bounds__(256, 1) void rnn_persist(
    const u16* __restrict__ Whh, const u16* __restrict__ Wih,
    const u16* __restrict__ GI0, const float* __restrict__ bih,
    const float* __restrict__ bhh, u16* __restrict__ hg /* [L][4][32][1024] */,
    int* flags /* [L][64][16] */, u16* __restrict__ H3, float* __restrict__ hsf) {
  const int bid = blockIdx.x;
  const int l = bid >> 6;
  const int n0 = (bid & 63) << 4;
  const int tid = threadIdx.x, lane = tid & 63, wid = tid >> 6;
  const int fr = lane & 15, q = lane >> 4;

  __shared__ float red[4][3][32][17];

  // ---- preload weights into registers ----
  bf16x8 w[3][16];
  if (l == 0) {
    const int kb = wid << 8;  // K-quarter of Whh[0]
#pragma unroll
    for (int g = 0; g < 3; ++g)
#pragma unroll
      for (int kt = 0; kt < 8; ++kt)
        w[g][kt] = *(const bf16x8*)(Whh + (((size_t)((g << 10) + n0 + fr)) << 10) +
                                    kb + kt * 32 + q * 8);
  } else {
    const u16* Wp = (wid < 2) ? (Wih + (((size_t)(l - 1) * TH) << 10))
                              : (Whh + (((size_t)l * TH) << 10));
    const int kb = (wid & 1) << 9;  // K-half
#pragma unroll
    for (int g = 0; g < 3; ++g)
#pragma unroll
      for (int kt = 0; kt < 16; ++kt)
        w[g][kt] = *(const bf16x8*)(Wp + (((size_t)((g << 10) + n0 + fr)) << 10) +
                                    kb + kt * 32 + q * 8);
  }

  // poll pointers (wave 0, lane i watches flag line i); clamp at boundaries
  const int* f_own = flags + ((l << 6) + lane) * 16;
  const int* f_m1 = (l > 0) ? flags + (((l - 1) << 6) + lane) * 16 : f_own;
  const int* f_p1 = (l < 3) ? flags + (((l + 1) << 6) + lane) * 16 : f_own;
  int* f_mine = flags + ((l << 6) + (bid & 63)) * 16;

  // gate-phase mapping: thread handles outputs (gb, gj) and (gb, gj+1)
  const int gb = tid >> 3;
  const int gjj = (tid & 7) * 2;
  const int gj = n0 + gjj;
  float bihv[3][2], bhhv[3][2];
#pragma unroll
  for (int g = 0; g < 3; ++g) {
    if (l > 0) {
      bihv[g][0] = bih[l * TH + (g << 10) + gj];
      bihv[g][1] = bih[l * TH + (g << 10) + gj + 1];
    } else {
      bihv[g][0] = bihv[g][1] = 0.f;
    }
    bhhv[g][0] = bhh[l * TH + (g << 10) + gj];
    bhhv[g][1] = bhh[l * TH + (g << 10) + gj + 1];
  }
  float hpriv0 = 0.f, hpriv1 = 0.f;  // fp32 master copy of this thread's h pair
  __syncthreads();

  for (int s = 0; s < NITER; ++s) {
    const int t = s - l;
    if (t < 0 || t >= S_) {
      if (tid == 0)
        __hip_atomic_fetch_add(f_mine, 1, __ATOMIC_RELEASE, __HIP_MEMORY_SCOPE_AGENT);
      continue;
    }
    const int prev = (s - 1) & 3;

    // ---- prefetch GI0 (independent of handshake) ----
    u32 g0p = 0, g1p = 0, g2p = 0;
    if (l == 0) {
      const u16* gp = GI0 + (size_t)((t << 5) + gb) * TH + gj;
      g0p = *(const u32*)gp;
      g1p = *(const u32*)(gp + 1024);
      g2p = *(const u32*)(gp + 2048);
    }

    // ---- wave-parallel distributed poll: loads+waitcnt FUSED in one asm ----
    if (wid == 0) {
      for (;;) {
        int fo, fm, fp;
        asm volatile(
            "global_load_dword %0, %3, off sc0 sc1\n\t"
            "global_load_dword %1, %4, off sc0 sc1\n\t"
            "global_load_dword %2, %5, off sc0 sc1\n\t"
            "s_waitcnt vmcnt(0)"
            : "=&v"(fo), "=&v"(fm), "=&v"(fp)
            : "v"(f_own), "v"(f_m1), "v"(f_p1)
            : "memory");
        __builtin_amdgcn_sched_barrier(0);
        bool ok = (fo >= s) && (fm >= s) && (fp >= s - 2);
        if (__all(ok)) break;
        __builtin_amdgcn_s_sleep(1);
      }
    }
    __syncthreads();

    // ---- MFMA phase: A-fragments straight from IF (sc0 sc1), weights from VGPRs ----
    f32x4 acc[2][3] = {};
    if (l == 0) {
      const u16* hp = hg + ((0 | prev) << 15);
      const int kb = wid << 8;
      bf16x8 afr[2][8];
#pragma unroll
      for (int mt = 0; mt < 2; ++mt)
#pragma unroll
        for (int kt = 0; kt < 8; ++kt) {
          const u16* p = hp + (((mt << 4) + fr) << 10) + kb + kt * 32 + q * 8;
          asm volatile("global_load_dwordx4 %0, %1, off sc0 sc1"
                       : "=v"(afr[mt][kt]) : "v"(p) : "memory");
        }
      asm volatile("s_waitcnt vmcnt(0)" ::: "memory");
      __builtin_amdgcn_sched_barrier(0);
#pragma unroll
      for (int kt = 0; kt < 8; ++kt)
#pragma unroll
        for (int g = 0; g < 3; ++g) {
          acc[0][g] = __builtin_amdgcn_mfma_f32_16x16x32_bf16(afr[0][kt], w[g][kt], acc[0][g], 0, 0, 0);
          acc[1][g] = __builtin_amdgcn_mfma_f32_16x16x32_bf16(afr[1][kt], w[g][kt], acc[1][g], 0, 0, 0);
        }
    } else {
      const u16* hsrc = (wid < 2) ? (hg + ((((l - 1) << 2) | prev) << 15))
                                  : (hg + (((l << 2) | prev) << 15));
      const int kb = (wid & 1) << 9;
      bf16x8 afr[2][16];
#pragma unroll
      for (int mt = 0; mt < 2; ++mt)
#pragma unroll
        for (int kt = 0; kt < 16; ++kt) {
          const u16* p = hsrc + (((mt << 4) + fr) << 10) + kb + kt * 32 + q * 8;
          asm volatile("global_load_dwordx4 %0, %1, off sc0 sc1"
                       : "=v"(afr[mt][kt]) : "v"(p) : "memory");
        }
      asm volatile("s_waitcnt vmcnt(0)" ::: "memory");
      __builtin_amdgcn_sched_barrier(0);
#pragma unroll
      for (int kt = 0; kt < 16; ++kt)
#pragma unroll
        for (int g = 0; g < 3; ++g) {
          acc[0][g] = __builtin_amdgcn_mfma_f32_16x16x32_bf16(afr[0][kt], w[g][kt], acc[0][g], 0, 0, 0);
          acc[1][g] = __builtin_amdgcn_mfma_f32_16x16x32_bf16(afr[1][kt], w[g][kt], acc[1][g], 0, 0, 0);
        }
    }

    // ---- write partial sums to LDS ----
#pragma unroll
    for (int mt = 0; mt < 2; ++mt)
#pragma unroll
      for (int g = 0; g < 3; ++g)
#pragma unroll
        for (int r = 0; r < 4; ++r)
          red[wid][g][(mt << 4) + q * 4 + r][fr] = acc[mt][g][r];
    __syncthreads();

    // ---- gate math: 2 outputs per thread ----
    float gi[3][2], gh[3][2];
#pragma unroll
    for (int g = 0; g < 3; ++g)
#pragma unroll
      for (int u = 0; u < 2; ++u) {
        float s01 = red[0][g][gb][gjj + u] + red[1][g][gb][gjj + u];
        float s23 = red[2][g][gb][gjj + u] + red[3][g][gb][gjj + u];
        if (l == 0) {
          gh[g][u] = s01 + s23 + bhhv[g][u];
        } else {
          gi[g][u] = s01 + bihv[g][u];
          gh[g][u] = s23 + bhhv[g][u];
        }
      }
    if (l == 0) {
      gi[0][0] = b2f((u16)(g0p & 0xffff));
      gi[0][1] = b2f((u16)(g0p >> 16));
      gi[1][0] = b2f((u16)(g1p & 0xffff));
      gi[1][1] = b2f((u16)(g1p >> 16));
      gi[2][0] = b2f((u16)(g2p & 0xffff));
      gi[2][1] = b2f((u16)(g2p >> 16));
    }
    float hn[2];
    float hpv[2] = {hpriv0, hpriv1};
#pragma unroll
    for (int u = 0; u < 2; ++u) {
      float rr = 1.f / (1.f + __expf(-(gi[0][u] + gh[0][u])));
      float zz = 1.f / (1.f + __expf(-(gi[1][u] + gh[1][u])));
      float xn = gi[2][u] + rr * gh[2][u];
      float nn = 1.f - 2.f / (__expf(2.f * xn) + 1.f);  // tanh, saturates correctly
      hn[u] = (1.f - zz) * nn + zz * hpv[u];
    }
    hpriv0 = hn[0];
    hpriv1 = hn[1];
    u32 hpack = pack2(hn[0], hn[1]);
    u32* hd = (u32*)(hg + (((l << 2) | (s & 3)) << 15) + (gb << 10) + gj);
    asm volatile("global_store_dword %0, %1, off sc0 sc1" ::"v"(hd), "v"(hpack)
                 : "memory");
    asm volatile("s_waitcnt vmcnt(0)" ::: "memory");
    __syncthreads();
    // RELEASE publication on the block's private flag line.
    if (tid == 0)
      __hip_atomic_fetch_add(f_mine, 1, __ATOMIC_RELEASE, __HIP_MEMORY_SCOPE_AGENT);
    // non-protocol stores off the release path:
    if (l == 3) *(u32*)(H3 + (((size_t)(t << 5) + gb) << 10) + gj) = hpack;
    if (t == S_ - 1) {
      hsf[((l << 5) + gb) * 1024 + gj] = hn[0];
      hsf[((l << 5) + gb) * 1024 + gj + 1] = hn[1];
    }
  }
}

extern "C" void kernel_launch(void* const* d_in, const int* in_sizes, int n_in,
                              void* d_out, int out_size, void* d_ws, size_t ws_size,
                              hipStream_t stream) {
  const float* x = (const float*)d_in[0];
  const float* pos = (const float*)d_in[1];
  const float* Wih0 = (const float*)d_in[2];
  const float* Wih = (const float*)d_in[3];
  const float* Whh = (const float*)d_in[4];
  const float* bih = (const float*)d_in[5];
  const float* bhh = (const float*)d_in[6];
  const float* Wout = (const float*)d_in[7];
  const float* bout = (const float*)d_in[8];
  float* out = (float*)d_out;

  char* ws = (char*)d_ws;
  size_t o = 0;
  u16* wih0_b = (u16*)(ws + o); o += (size_t)TH * D_ * 2;
  u16* wih_b  = (u16*)(ws + o); o += (size_t)3 * TH * H_ * 2;
  u16* whh_b  = (u16*)(ws + o); o += (size_t)4 * TH * H_ * 2;
  u16* wout_b = (u16*)(ws + o); o += (size_t)D_ * H_ * 2;
  u16* GI0    = (u16*)(ws + o); o += (size_t)S_ * B_ * TH * 2;
  u16* H3     = (u16*)(ws + o); o += (size_t)S_ * B_ * H_ * 2;
  u16* hg     = (u16*)(ws + o); o += (size_t)L_ * 4 * B_ * H_ * 2;
  int* flags  = (int*)(ws + o); o += (size_t)L_ * 64 * 16 * 4;

  cvt_kernel<<<512, 256, 0, stream>>>(Wih0, wih0_b, TH * D_ / 4);
  cvt_kernel<<<512, 256, 0, stream>>>(Wih, wih_b, 3 * TH * H_ / 4);
  cvt_kernel<<<512, 256, 0, stream>>>(Whh, whh_b, 4 * TH * H_ / 4);
  cvt_kernel<<<512, 256, 0, stream>>>(Wout, wout_b, D_ * H_ / 4);
  hipMemsetAsync(hg, 0, (size_t)L_ * 4 * B_ * H_ * 2 + (size_t)L_ * 64 * 16 * 4, stream);

  gi0_gemm<<<dim3(TH / 64, (S_ * B_) / 64), 256, 0, stream>>>(x, pos, wih0_b, bih, GI0);

  float* hsf = out + (size_t)B_ * S_ * D_;
  rnn_persist<<<256, 256, 0, stream>>>(whh_b, wih_b, GI0, bih, bhh, hg, flags, H3, hsf);

  out_gemm<<<dim3(D_ / 64, (S_ * B_) / 64), 256, 0, stream>>>(H3, wout_b, bout, out);
}

// Round 10
// 3809.107 us; speedup vs baseline: 3.8205x; 1.4663x over previous
//
#include <hip/hip_runtime.h>

#define B_ 32
#define S_ 512
#define D_ 768
#define H_ 1024
#define L_ 4
#define TH 3072  // 3*H
#define NPL 64   // blocks per layer
#define NITER (S_ + L_ - 1)

typedef unsigned short u16;
typedef unsigned int u32;
typedef __bf16 bf16x8 __attribute__((ext_vector_type(8)));
typedef float f32x4 __attribute__((ext_vector_type(4)));

__device__ __forceinline__ u16 f2b(float f) {
  unsigned u = __builtin_bit_cast(unsigned, f);
  u += 0x7fffu + ((u >> 16) & 1u);  // RNE
  return (u16)(u >> 16);
}
__device__ __forceinline__ float b2f(u16 h) {
  return __builtin_bit_cast(float, ((unsigned)h) << 16);
}
__device__ __forceinline__ unsigned pack2(float a, float b) {
  return (unsigned)f2b(a) | ((unsigned)f2b(b) << 16);
}

// ---------------- fp32 -> bf16 convert ----------------
__global__ __launch_bounds__(256) void cvt_kernel(const float* __restrict__ src,
                                                  u16* __restrict__ dst, int n4) {
  int i = blockIdx.x * 256 + threadIdx.x;
  int stride = gridDim.x * 256;
  for (; i < n4; i += stride) {
    float4 f = ((const float4*)src)[i];
    uint2 o;
    o.x = pack2(f.x, f.y);
    o.y = pack2(f.z, f.w);
    ((uint2*)dst)[i] = o;
  }
}

// ---------------- GI0 = (x+pos) @ W_ih0^T + b_ih[0]  -> bf16 [S*B][3072] ----------------
__global__ __launch_bounds__(256) void gi0_gemm(const float* __restrict__ x,
                                                const float* __restrict__ pos,
                                                const u16* __restrict__ W0,
                                                const float* __restrict__ bih0,
                                                u16* __restrict__ GI0) {
  const int n0 = blockIdx.x * 64;
  const int m0 = blockIdx.y * 64;
  __shared__ u16 sA[64 * 72];
  __shared__ u16 sB[64 * 72];
  const int tid = threadIdx.x, lane = tid & 63, wid = tid >> 6;
  const int wm = wid >> 1, wn = wid & 1;
  const int fr = lane & 15, fk = (lane >> 4) * 8;
  f32x4 acc[2][2] = {};
  for (int k0 = 0; k0 < D_; k0 += 64) {
    for (int sl = tid; sl < 512; sl += 256) {
      int r = sl >> 3, c = sl & 7;
      int m = m0 + r, si = m >> 5, b = m & 31;
      const float* xp = x + (size_t)((b << 9) + si) * D_ + k0 + c * 8;
      const float* pp = pos + (size_t)si * D_ + k0 + c * 8;
      float4 x0 = *(const float4*)xp, x1 = *(const float4*)(xp + 4);
      float4 p0 = *(const float4*)pp, p1 = *(const float4*)(pp + 4);
      uint4 o;
      o.x = pack2(x0.x + p0.x, x0.y + p0.y);
      o.y = pack2(x0.z + p0.z, x0.w + p0.w);
      o.z = pack2(x1.x + p1.x, x1.y + p1.y);
      o.w = pack2(x1.z + p1.z, x1.w + p1.w);
      *(uint4*)&sA[r * 72 + c * 8] = o;
      *(uint4*)&sB[r * 72 + c * 8] =
          *(const uint4*)(W0 + (size_t)(n0 + r) * D_ + k0 + c * 8);
    }
    __syncthreads();
#pragma unroll
    for (int kk = 0; kk < 2; ++kk) {
      bf16x8 a0 = *(const bf16x8*)&sA[(wm * 32 + fr) * 72 + kk * 32 + fk];
      bf16x8 a1 = *(const bf16x8*)&sA[(wm * 32 + 16 + fr) * 72 + kk * 32 + fk];
      bf16x8 b0 = *(const bf16x8*)&sB[(wn * 32 + fr) * 72 + kk * 32 + fk];
      bf16x8 b1 = *(const bf16x8*)&sB[(wn * 32 + 16 + fr) * 72 + kk * 32 + fk];
      acc[0][0] = __builtin_amdgcn_mfma_f32_16x16x32_bf16(a0, b0, acc[0][0], 0, 0, 0);
      acc[0][1] = __builtin_amdgcn_mfma_f32_16x16x32_bf16(a0, b1, acc[0][1], 0, 0, 0);
      acc[1][0] = __builtin_amdgcn_mfma_f32_16x16x32_bf16(a1, b0, acc[1][0], 0, 0, 0);
      acc[1][1] = __builtin_amdgcn_mfma_f32_16x16x32_bf16(a1, b1, acc[1][1], 0, 0, 0);
    }
    __syncthreads();
  }
#pragma unroll
  for (int mi = 0; mi < 2; ++mi)
#pragma unroll
    for (int ni = 0; ni < 2; ++ni)
#pragma unroll
      for (int r = 0; r < 4; ++r) {
        int m = m0 + wm * 32 + mi * 16 + (lane >> 4) * 4 + r;
        int n = n0 + wn * 32 + ni * 16 + fr;
        GI0[(size_t)m * TH + n] = f2b(acc[mi][ni][r] + bih0[n]);
      }
}

// ---------------- out_seq = H3 @ W_out^T + b_out ----------------
__global__ __launch_bounds__(256) void out_gemm(const u16* __restrict__ H3,
                                                const u16* __restrict__ Wo,
                                                const float* __restrict__ bo,
                                                float* __restrict__ out) {
  const int n0 = blockIdx.x * 64;
  const int m0 = blockIdx.y * 64;
  __shared__ u16 sA[64 * 72];
  __shared__ u16 sB[64 * 72];
  const int tid = threadIdx.x, lane = tid & 63, wid = tid >> 6;
  const int wm = wid >> 1, wn = wid & 1;
  const int fr = lane & 15, fk = (lane >> 4) * 8;
  f32x4 acc[2][2] = {};
  for (int k0 = 0; k0 < H_; k0 += 64) {
    for (int sl = tid; sl < 512; sl += 256) {
      int r = sl >> 3, c = sl & 7;
      int m = m0 + r, b = m >> 9, si = m & 511;
      *(uint4*)&sA[r * 72 + c * 8] =
          *(const uint4*)(H3 + (size_t)((si << 5) + b) * H_ + k0 + c * 8);
      *(uint4*)&sB[r * 72 + c * 8] =
          *(const uint4*)(Wo + (size_t)(n0 + r) * H_ + k0 + c * 8);
    }
    __syncthreads();
#pragma unroll
    for (int kk = 0; kk < 2; ++kk) {
      bf16x8 a0 = *(const bf16x8*)&sA[(wm * 32 + fr) * 72 + kk * 32 + fk];
      bf16x8 a1 = *(const bf16x8*)&sA[(wm * 32 + 16 + fr) * 72 + kk * 32 + fk];
      bf16x8 b0 = *(const bf16x8*)&sB[(wn * 32 + fr) * 72 + kk * 32 + fk];
      bf16x8 b1 = *(const bf16x8*)&sB[(wn * 32 + 16 + fr) * 72 + kk * 32 + fk];
      acc[0][0] = __builtin_amdgcn_mfma_f32_16x16x32_bf16(a0, b0, acc[0][0], 0, 0, 0);
      acc[0][1] = __builtin_amdgcn_mfma_f32_16x16x32_bf16(a0, b1, acc[0][1], 0, 0, 0);
      acc[1][0] = __builtin_amdgcn_mfma_f32_16x16x32_bf16(a1, b0, acc[1][0], 0, 0, 0);
      acc[1][1] = __builtin_amdgcn_mfma_f32_16x16x32_bf16(a1, b1, acc[1][1], 0, 0, 0);
    }
    __syncthreads();
  }
#pragma unroll
  for (int mi = 0; mi < 2; ++mi)
#pragma unroll
    for (int ni = 0; ni < 2; ++ni)
#pragma unroll
      for (int r = 0; r < 4; ++r) {
        int m = m0 + wm * 32 + mi * 16 + (lane >> 4) * 4 + r;
        int n = n0 + wn * 32 + ni * 16 + fr;
        out[(size_t)m * D_ + n] = acc[mi][ni][r] + bo[n];
      }
}

// ---------------- persistent weight-stationary GRU scan ----------------
// 256 blocks (1/CU). Distributed flags: flags[L][64], one 64B line per block,
// flag = #completed iterations. Publication: h stores are sc0/sc1 write-
// through; vmcnt(0) acks them at the device coherence point; barrier; then a
// PLAIN sc0/sc1 flag store (no RMW, no wbl2 drain). Poll (rule #18): all 3
// flag loads + s_waitcnt fused in ONE asm so dependent compares can't slip
// between loads and waitcnt.
// h ring [L][4][32][1024]: writer (l,s)->buf s&3; WAR vs (l+1 @ s-3) guarded
// by flag[l+1] >= s-2; producers by flag[l-1] >= s, flag[l] >= s.
__global__ __launch_bounds__(256, 1) void rnn_persist(
    const u16* __restrict__ Whh, const u16* __restrict__ Wih,
    const u16* __restrict__ GI0, const float* __restrict__ bih,
    const float* __restrict__ bhh, u16* __restrict__ hg /* [L][4][32][1024] */,
    int* flags /* [L][64][16] */, u16* __restrict__ H3, float* __restrict__ hsf) {
  const int bid = blockIdx.x;
  const int l = bid >> 6;
  const int n0 = (bid & 63) << 4;
  const int tid = threadIdx.x, lane = tid & 63, wid = tid >> 6;
  const int fr = lane & 15, q = lane >> 4;

  __shared__ float red[4][3][32][17];

  // ---- preload weights into registers ----
  bf16x8 w[3][16];
  if (l == 0) {
    const int kb = wid << 8;  // K-quarter of Whh[0]
#pragma unroll
    for (int g = 0; g < 3; ++g)
#pragma unroll
      for (int kt = 0; kt < 8; ++kt)
        w[g][kt] = *(const bf16x8*)(Whh + (((size_t)((g << 10) + n0 + fr)) << 10) +
                                    kb + kt * 32 + q * 8);
  } else {
    const u16* Wp = (wid < 2) ? (Wih + (((size_t)(l - 1) * TH) << 10))
                              : (Whh + (((size_t)l * TH) << 10));
    const int kb = (wid & 1) << 9;  // K-half
#pragma unroll
    for (int g = 0; g < 3; ++g)
#pragma unroll
      for (int kt = 0; kt < 16; ++kt)
        w[g][kt] = *(const bf16x8*)(Wp + (((size_t)((g << 10) + n0 + fr)) << 10) +
                                    kb + kt * 32 + q * 8);
  }

  // poll pointers (wave 0, lane i watches flag line i); clamp at boundaries
  const int* f_own = flags + ((l << 6) + lane) * 16;
  const int* f_m1 = (l > 0) ? flags + (((l - 1) << 6) + lane) * 16 : f_own;
  const int* f_p1 = (l < 3) ? flags + (((l + 1) << 6) + lane) * 16 : f_own;
  int* f_mine = flags + ((l << 6) + (bid & 63)) * 16;

  // gate-phase mapping: thread handles outputs (gb, gj) and (gb, gj+1)
  const int gb = tid >> 3;
  const int gjj = (tid & 7) * 2;
  const int gj = n0 + gjj;
  float bihv[3][2], bhhv[3][2];
#pragma unroll
  for (int g = 0; g < 3; ++g) {
    if (l > 0) {
      bihv[g][0] = bih[l * TH + (g << 10) + gj];
      bihv[g][1] = bih[l * TH + (g << 10) + gj + 1];
    } else {
      bihv[g][0] = bihv[g][1] = 0.f;
    }
    bhhv[g][0] = bhh[l * TH + (g << 10) + gj];
    bhhv[g][1] = bhh[l * TH + (g << 10) + gj + 1];
  }
  float hpriv0 = 0.f, hpriv1 = 0.f;  // fp32 master copy of this thread's h pair
  __syncthreads();

  for (int s = 0; s < NITER; ++s) {
    const int t = s - l;
    if (t < 0 || t >= S_) {
      if (tid == 0) {
        int v = s + 1;
        asm volatile("global_store_dword %0, %1, off sc0 sc1" ::"v"(f_mine), "v"(v)
                     : "memory");
      }
      continue;
    }
    const int prev = (s - 1) & 3;

    // ---- prefetch GI0 (independent of handshake) ----
    u32 g0p = 0, g1p = 0, g2p = 0;
    if (l == 0) {
      const u16* gp = GI0 + (size_t)((t << 5) + gb) * TH + gj;
      g0p = *(const u32*)gp;
      g1p = *(const u32*)(gp + 1024);
      g2p = *(const u32*)(gp + 2048);
    }

    // ---- wave-parallel distributed poll: loads+waitcnt FUSED in one asm ----
    if (wid == 0) {
      for (;;) {
        int fo, fm, fp;
        asm volatile(
            "global_load_dword %0, %3, off sc0 sc1\n\t"
            "global_load_dword %1, %4, off sc0 sc1\n\t"
            "global_load_dword %2, %5, off sc0 sc1\n\t"
            "s_waitcnt vmcnt(0)"
            : "=&v"(fo), "=&v"(fm), "=&v"(fp)
            : "v"(f_own), "v"(f_m1), "v"(f_p1)
            : "memory");
        __builtin_amdgcn_sched_barrier(0);
        bool ok = (fo >= s) && (fm >= s) && (fp >= s - 2);
        if (__all(ok)) break;
        __builtin_amdgcn_s_sleep(1);
      }
    }
    __syncthreads();

    // ---- MFMA phase: A-fragments straight from IF (sc0 sc1), weights from VGPRs ----
    f32x4 acc[2][3] = {};
    if (l == 0) {
      const u16* hp = hg + ((0 | prev) << 15);
      const int kb = wid << 8;
      bf16x8 afr[2][8];
#pragma unroll
      for (int mt = 0; mt < 2; ++mt)
#pragma unroll
        for (int kt = 0; kt < 8; ++kt) {
          const u16* p = hp + (((mt << 4) + fr) << 10) + kb + kt * 32 + q * 8;
          asm volatile("global_load_dwordx4 %0, %1, off sc0 sc1"
                       : "=v"(afr[mt][kt]) : "v"(p) : "memory");
        }
      asm volatile("s_waitcnt vmcnt(0)" ::: "memory");
      __builtin_amdgcn_sched_barrier(0);
#pragma unroll
      for (int kt = 0; kt < 8; ++kt)
#pragma unroll
        for (int g = 0; g < 3; ++g) {
          acc[0][g] = __builtin_amdgcn_mfma_f32_16x16x32_bf16(afr[0][kt], w[g][kt], acc[0][g], 0, 0, 0);
          acc[1][g] = __builtin_amdgcn_mfma_f32_16x16x32_bf16(afr[1][kt], w[g][kt], acc[1][g], 0, 0, 0);
        }
    } else {
      const u16* hsrc = (wid < 2) ? (hg + ((((l - 1) << 2) | prev) << 15))
                                  : (hg + (((l << 2) | prev) << 15));
      const int kb = (wid & 1) << 9;
      bf16x8 afr[2][16];
#pragma unroll
      for (int mt = 0; mt < 2; ++mt)
#pragma unroll
        for (int kt = 0; kt < 16; ++kt) {
          const u16* p = hsrc + (((mt << 4) + fr) << 10) + kb + kt * 32 + q * 8;
          asm volatile("global_load_dwordx4 %0, %1, off sc0 sc1"
                       : "=v"(afr[mt][kt]) : "v"(p) : "memory");
        }
      asm volatile("s_waitcnt vmcnt(0)" ::: "memory");
      __builtin_amdgcn_sched_barrier(0);
#pragma unroll
      for (int kt = 0; kt < 16; ++kt)
#pragma unroll
        for (int g = 0; g < 3; ++g) {
          acc[0][g] = __builtin_amdgcn_mfma_f32_16x16x32_bf16(afr[0][kt], w[g][kt], acc[0][g], 0, 0, 0);
          acc[1][g] = __builtin_amdgcn_mfma_f32_16x16x32_bf16(afr[1][kt], w[g][kt], acc[1][g], 0, 0, 0);
        }
    }

    // ---- write partial sums to LDS ----
#pragma unroll
    for (int mt = 0; mt < 2; ++mt)
#pragma unroll
      for (int g = 0; g < 3; ++g)
#pragma unroll
        for (int r = 0; r < 4; ++r)
          red[wid][g][(mt << 4) + q * 4 + r][fr] = acc[mt][g][r];
    __syncthreads();

    // ---- gate math: 2 outputs per thread ----
    float gi[3][2], gh[3][2];
#pragma unroll
    for (int g = 0; g < 3; ++g)
#pragma unroll
      for (int u = 0; u < 2; ++u) {
        float s01 = red[0][g][gb][gjj + u] + red[1][g][gb][gjj + u];
        float s23 = red[2][g][gb][gjj + u] + red[3][g][gb][gjj + u];
        if (l == 0) {
          gh[g][u] = s01 + s23 + bhhv[g][u];
        } else {
          gi[g][u] = s01 + bihv[g][u];
          gh[g][u] = s23 + bhhv[g][u];
        }
      }
    if (l == 0) {
      gi[0][0] = b2f((u16)(g0p & 0xffff));
      gi[0][1] = b2f((u16)(g0p >> 16));
      gi[1][0] = b2f((u16)(g1p & 0xffff));
      gi[1][1] = b2f((u16)(g1p >> 16));
      gi[2][0] = b2f((u16)(g2p & 0xffff));
      gi[2][1] = b2f((u16)(g2p >> 16));
    }
    float hn[2];
    float hpv[2] = {hpriv0, hpriv1};
#pragma unroll
    for (int u = 0; u < 2; ++u) {
      float rr = 1.f / (1.f + __expf(-(gi[0][u] + gh[0][u])));
      float zz = 1.f / (1.f + __expf(-(gi[1][u] + gh[1][u])));
      float xn = gi[2][u] + rr * gh[2][u];
      float nn = 1.f - 2.f / (__expf(2.f * xn) + 1.f);  // tanh, saturates correctly
      hn[u] = (1.f - zz) * nn + zz * hpv[u];
    }
    hpriv0 = hn[0];
    hpriv1 = hn[1];
    u32 hpack = pack2(hn[0], hn[1]);
    u32* hd = (u32*)(hg + (((l << 2) | (s & 3)) << 15) + (gb << 10) + gj);
    asm volatile("global_store_dword %0, %1, off sc0 sc1" ::"v"(hd), "v"(hpack)
                 : "memory");
    asm volatile("s_waitcnt vmcnt(0)" ::: "memory");
    __syncthreads();
    // PLAIN-store publication on the block's private flag line (h already
    // acked at the coherence point by the per-thread vmcnt(0) above).
    if (tid == 0) {
      int v = s + 1;
      asm volatile("global_store_dword %0, %1, off sc0 sc1" ::"v"(f_mine), "v"(v)
                   : "memory");
    }
    // non-protocol stores off the release path:
    if (l == 3) *(u32*)(H3 + (((size_t)(t << 5) + gb) << 10) + gj) = hpack;
    if (t == S_ - 1) {
      hsf[((l << 5) + gb) * 1024 + gj] = hn[0];
      hsf[((l << 5) + gb) * 1024 + gj + 1] = hn[1];
    }
  }
}

extern "C" void kernel_launch(void* const* d_in, const int* in_sizes, int n_in,
                              void* d_out, int out_size, void* d_ws, size_t ws_size,
                              hipStream_t stream) {
  const float* x = (const float*)d_in[0];
  const float* pos = (const float*)d_in[1];
  const float* Wih0 = (const float*)d_in[2];
  const float* Wih = (const float*)d_in[3];
  const float* Whh = (const float*)d_in[4];
  const float* bih = (const float*)d_in[5];
  const float* bhh = (const float*)d_in[6];
  const float* Wout = (const float*)d_in[7];
  const float* bout = (const float*)d_in[8];
  float* out = (float*)d_out;

  char* ws = (char*)d_ws;
  size_t o = 0;
  u16* wih0_b = (u16*)(ws + o); o += (size_t)TH * D_ * 2;
  u16* wih_b  = (u16*)(ws + o); o += (size_t)3 * TH * H_ * 2;
  u16* whh_b  = (u16*)(ws + o); o += (size_t)4 * TH * H_ * 2;
  u16* wout_b = (u16*)(ws + o); o += (size_t)D_ * H_ * 2;
  u16* GI0    = (u16*)(ws + o); o += (size_t)S_ * B_ * TH * 2;
  u16* H3     = (u16*)(ws + o); o += (size_t)S_ * B_ * H_ * 2;
  u16* hg     = (u16*)(ws + o); o += (size_t)L_ * 4 * B_ * H_ * 2;
  int* flags  = (int*)(ws + o); o += (size_t)L_ * 64 * 16 * 4;

  cvt_kernel<<<512, 256, 0, stream>>>(Wih0, wih0_b, TH * D_ / 4);
  cvt_kernel<<<512, 256, 0, stream>>>(Wih, wih_b, 3 * TH * H_ / 4);
  cvt_kernel<<<512, 256, 0, stream>>>(Whh, whh_b, 4 * TH * H_ / 4);
  cvt_kernel<<<512, 256, 0, stream>>>(Wout, wout_b, D_ * H_ / 4);
  hipMemsetAsync(hg, 0, (size_t)L_ * 4 * B_ * H_ * 2 + (size_t)L_ * 64 * 16 * 4, stream);

  gi0_gemm<<<dim3(TH / 64, (S_ * B_) / 64), 256, 0, stream>>>(x, pos, wih0_b, bih, GI0);

  float* hsf = out + (size_t)B_ * S_ * D_;
  rnn_persist<<<256, 256, 0, stream>>>(whh_b, wih_b, GI0, bih, bhh, hg, flags, H3, hsf);

  out_gemm<<<dim3(D_ / 64, (S_ * B_) / 64), 256, 0, stream>>>(H3, wout_b, bout, out);
}